// Round 6
// baseline (263.519 us; speedup 1.0000x reference)
//
#include <hip/hip_runtime.h>
#include <math.h>

#define NS   2048
#define TL   81
#define NBN  15
#define DA   48
#define SQL  31
#define KD   1488   // SEQ*D_ATT
#define DL   256
#define MID  40

#define INV_SQRT_BN 0.99999500003749969f   // 1/sqrt(1+1e-5)
#define SCALE_ATT   0.35355339059327373f   // 1/sqrt(8)

// ---------------- Kernel 1: per-sample encoder + LN + attention + proj -> y2 ----------------
// Byte-exact round-0 version (measured ~70us). Do not touch: 3 restructures all regressed.
__global__ __launch_bounds__(256)
void attn_kernel(const float* __restrict__ x5, const float* __restrict__ noise,
                 const float* __restrict__ enc_w, const float* __restrict__ enc_b,
                 const float* __restrict__ enc_g, const float* __restrict__ enc_bb,
                 const float* __restrict__ ln_a, const float* __restrict__ ln_b,
                 const float* __restrict__ wq, const float* __restrict__ bq,
                 const float* __restrict__ wk, const float* __restrict__ bk,
                 const float* __restrict__ wv, const float* __restrict__ bv,
                 const float* __restrict__ wo, const float* __restrict__ bo,
                 float* __restrict__ y2)
{
    __shared__ float s93[96];
    __shared__ float sy[32*49];                     // y after enc+relu  [s][f], stride 49
    __shared__ float sh[32*49];                     // h after LN; reused as ctx
    __shared__ float sW[3*48*49];                   // wq|wk|wv staged; arr0 reused for wo
    __shared__ __align__(16) float sQKV[32*148];    // [s][arr*48+f]
    __shared__ float smean[32], sinv[32];

    const int tid = threadIdx.x;
    const int n = blockIdx.x;

    // ---- phase 0: load mid-frame (root-subtracted) + noise; stage wq/wk/wv ----
    if (tid < 93) {
        float v;
        if (tid < 48) {
            const float* base = x5 + ((size_t)n*TL + MID)*48;
            v = base[tid] - base[tid % 3];          // x5 - root (joint 0)
        } else {
            v = noise[(size_t)n*45 + (tid-48)];
        }
        s93[tid] = v;
    }
    #pragma unroll
    for (int l=0; l<9; l++){
        int idx = tid + l*256;                      // 0..2303
        int f = idx/48, c = idx - f*48;
        int o = f*49 + c;
        sW[o]        = wq[idx];
        sW[2352 + o] = wk[idx];
        sW[4704 + o] = wv[idx];
    }
    __syncthreads();

    // ---- phase 1: encoder + BN + relu ----
    for (int idx=tid; idx<SQL*DA; idx+=256){
        int s = idx/48, f = idx - s*48;
        float a = enc_b[f]
                + s93[s*3+0]*enc_w[f*3+0]
                + s93[s*3+1]*enc_w[f*3+1]
                + s93[s*3+2]*enc_w[f*3+2];
        float v = a * (enc_g[f]*INV_SQRT_BN) + enc_bb[f];
        sy[s*49+f] = fmaxf(v, 0.0f);
    }
    __syncthreads();

    // ---- phase 2: layer-norm stats (divisor 47, eps on std) ----
    if (tid < SQL){
        float m = 0.f;
        for (int f=0; f<48; f++) m += sy[tid*49+f];
        m *= (1.0f/48.0f);
        float vs = 0.f;
        for (int f=0; f<48; f++){ float d = sy[tid*49+f]-m; vs += d*d; }
        float sd = sqrtf(vs * (1.0f/47.0f));
        smean[tid] = m;
        sinv[tid]  = 1.0f/(sd + 1e-6f);
    }
    __syncthreads();

    // ---- phase 3: apply LN ----
    for (int idx=tid; idx<SQL*DA; idx+=256){
        int s = idx/48, f = idx - s*48;
        sh[s*49+f] = ln_a[f]*(sy[s*49+f]-smean[s])*sinv[s] + ln_b[f];
    }
    __syncthreads();

    // ---- phase 4: QKV (register-tiled 4s x 6F, 192 threads) ----
    if (tid < 192){
        const int sg = tid/24, fg = tid - (tid/24)*24;
        const int arr = fg >> 3;                    // 0..2 -> q,k,v
        const int f0  = (fg & 7)*6;
        const float* wb = sW + arr*2352 + f0*49;
        const float* hb = sh + sg*4*49;
        float a0[6]={0,0,0,0,0,0}, a1[6]={0,0,0,0,0,0};
        float a2[6]={0,0,0,0,0,0}, a3[6]={0,0,0,0,0,0};
        for (int c=0; c<48; c++){
            float h0 = hb[c], h1 = hb[49+c], h2 = hb[98+c], h3 = hb[147+c];
            #pragma unroll
            for (int i=0;i<6;i++){
                float w = wb[i*49+c];
                a0[i] += h0*w; a1[i] += h1*w; a2[i] += h2*w; a3[i] += h3*w;
            }
        }
        const float* bias = (arr==0)? bq : (arr==1? bk : bv);
        #pragma unroll
        for (int i=0;i<6;i++){
            float b = bias[f0+i];
            int col = arr*48 + f0 + i;
            sQKV[(sg*4+0)*148 + col] = a0[i] + b;
            sQKV[(sg*4+1)*148 + col] = a1[i] + b;
            sQKV[(sg*4+2)*148 + col] = a2[i] + b;
            sQKV[(sg*4+3)*148 + col] = a3[i] + b;   // s=31 row is scratch, never read
        }
    }
    __syncthreads();

    // ---- phase 5: stage wo into sW arr0 (dead); attention (186 threads) -> ctx into sh ----
    #pragma unroll
    for (int l=0; l<9; l++){
        int idx = tid + l*256;
        sW[(idx/48)*49 + (idx%48)] = wo[idx];
    }
    if (tid < 186){
        const int hd = tid/31, qi = tid - (tid/31)*31;
        const float4 q0 = *(const float4*)(sQKV + qi*148 + hd*8);
        const float4 q1 = *(const float4*)(sQKV + qi*148 + hd*8 + 4);
        float sc[31]; float mx = -1e30f;
        for (int ki=0; ki<31; ki++){
            const float4 k0 = *(const float4*)(sQKV + ki*148 + 48 + hd*8);
            const float4 k1 = *(const float4*)(sQKV + ki*148 + 48 + hd*8 + 4);
            float d = q0.x*k0.x + q0.y*k0.y + q0.z*k0.z + q0.w*k0.w
                    + q1.x*k1.x + q1.y*k1.y + q1.z*k1.z + q1.w*k1.w;
            d *= SCALE_ATT;
            sc[ki] = d; mx = fmaxf(mx, d);
        }
        float ssum = 0.f;
        for (int ki=0; ki<31; ki++){ float e = expf(sc[ki]-mx); sc[ki]=e; ssum += e; }
        float rin = 1.0f/ssum;
        float4 c0 = {0,0,0,0}, c1 = {0,0,0,0};
        for (int ki=0; ki<31; ki++){
            float p = sc[ki];
            const float4 v0 = *(const float4*)(sQKV + ki*148 + 96 + hd*8);
            const float4 v1 = *(const float4*)(sQKV + ki*148 + 96 + hd*8 + 4);
            c0.x += p*v0.x; c0.y += p*v0.y; c0.z += p*v0.z; c0.w += p*v0.w;
            c1.x += p*v1.x; c1.y += p*v1.y; c1.z += p*v1.z; c1.w += p*v1.w;
        }
        float* cb = sh + qi*49 + hd*8;              // ctx overwrites h (dead)
        cb[0]=c0.x*rin; cb[1]=c0.y*rin; cb[2]=c0.z*rin; cb[3]=c0.w*rin;
        cb[4]=c1.x*rin; cb[5]=c1.y*rin; cb[6]=c1.z*rin; cb[7]=c1.w*rin;
    }
    __syncthreads();

    // ---- phase 6: proj + residual -> y2 (register-tiled 2s x 4f, 192 threads) ----
    if (tid < 192){
        const int sg = tid/12, fg = tid - (tid/12)*12;
        const int f0 = fg*4;
        const float* wb = sW + f0*49;               // wo
        const float* cb = sh + sg*2*49;             // ctx
        float a0[4]={0,0,0,0}, a1[4]={0,0,0,0};
        for (int c=0; c<48; c++){
            float x0 = cb[c], x1 = cb[49+c];
            #pragma unroll
            for (int i=0;i<4;i++){
                float w = wb[i*49+c];
                a0[i] += x0*w; a1[i] += x1*w;
            }
        }
        {
            int s = sg*2;
            if (s < 31){
                float* dst = y2 + (size_t)n*KD + s*48 + f0;
                const float* yb = sy + s*49 + f0;
                #pragma unroll
                for (int i=0;i<4;i++) dst[i] = yb[i] + a0[i] + bo[f0+i];
            }
        }
        {
            int s = sg*2+1;
            if (s < 31){
                float* dst = y2 + (size_t)n*KD + s*48 + f0;
                const float* yb = sy + s*49 + f0;
                #pragma unroll
                for (int i=0;i<4;i++) dst[i] = yb[i] + a1[i] + bo[f0+i];
            }
        }
    }
}

// ---------------- Kernel 2: C = y2 @ w1^T, K-split 12 (was 6) ----------------
// 1536 blocks -> 6 blocks/CU (was 3): doubles independent barrier-groups per CU
// to hide the global-load -> barrier -> LDS-store chain. KCH=4: staging = exactly
// 1 float4/thread for B, tid<16 for A. Same inner FMA pattern as the round-4 anchor.
#define KSP 12
#define KPS 124     // 1488/12
#define KCH 4

__global__ __launch_bounds__(256)
void gemm1_kernel(const float* __restrict__ y2, const float* __restrict__ w1,
                  float* __restrict__ y3p)
{
    __shared__ __align__(16) float sB[KCH*256];     // [kk][n]  4KB
    __shared__ __align__(16) float sA[KCH*20];      // [kk][m]  320B
    const int tid = threadIdx.x;
    const int bx = blockIdx.x;                      // 1536 blocks
    const int m0 = (bx & 127) * 16;
    const int split = bx >> 7;                      // 0..11
    const int ks0 = split * KPS;
    const int c0 = (tid & 15)*4 + (tid >> 6)*64;    // output cols c0..c0+3
    const int r0 = ((tid >> 4) & 3)*4;              // output rows r0..r0+3

    float acc[4][4];
    #pragma unroll
    for (int i=0;i<4;i++)
        #pragma unroll
        for (int j=0;j<4;j++) acc[i][j]=0.f;

    for (int ch=0; ch<31; ch++){
        const int k0 = ks0 + ch*KCH;
        // global loads first (latency overlaps barrier wait on other waves)
        float4 bv = *(const float4*)(w1 + (size_t)tid*KD + k0);
        float4 av;
        if (tid < 16) av = *(const float4*)(y2 + (size_t)(m0+tid)*KD + k0);
        __syncthreads();
        // transposed stores: bank = tid%32 across lanes -> 2-way (free)
        sB[0*256 + tid] = bv.x;  sB[1*256 + tid] = bv.y;
        sB[2*256 + tid] = bv.z;  sB[3*256 + tid] = bv.w;
        if (tid < 16){
            sA[0*20 + tid] = av.x;  sA[1*20 + tid] = av.y;
            sA[2*20 + tid] = av.z;  sA[3*20 + tid] = av.w;
        }
        __syncthreads();
        #pragma unroll
        for (int kk=0; kk<KCH; kk++){
            float4 b = *(const float4*)(sB + kk*256 + c0);  // 16 addr x 4-lane bcast
            float4 a = *(const float4*)(sA + kk*20 + r0);   // 4 addr broadcast
            acc[0][0] += a.x*b.x; acc[0][1] += a.x*b.y; acc[0][2] += a.x*b.z; acc[0][3] += a.x*b.w;
            acc[1][0] += a.y*b.x; acc[1][1] += a.y*b.y; acc[1][2] += a.y*b.z; acc[1][3] += a.y*b.w;
            acc[2][0] += a.z*b.x; acc[2][1] += a.z*b.y; acc[2][2] += a.z*b.z; acc[2][3] += a.z*b.w;
            acc[3][0] += a.w*b.x; acc[3][1] += a.w*b.y; acc[3][2] += a.w*b.z; acc[3][3] += a.w*b.w;
        }
    }

    float* dst = y3p + (size_t)split*NS*DL;
    #pragma unroll
    for (int i=0;i<4;i++){
        float4 v; v.x=acc[i][0]; v.y=acc[i][1]; v.z=acc[i][2]; v.w=acc[i][3];
        *(float4*)(dst + (size_t)(m0+r0+i)*DL + c0) = v;
    }
}

// ---------------- Kernel 3: sum 12 K-splits + bias/BN/leaky; y4 = leaky(y3 @ w2^T + b2); axis/theta ----------------
// 256 blocks x 8 samples (measured better than 128x16)
__global__ __launch_bounds__(256)
void head_kernel(const float* __restrict__ y3p, const float* __restrict__ w2,
                 const float* __restrict__ b2, const float* __restrict__ b1,
                 const float* __restrict__ g1, const float* __restrict__ bb1,
                 float* __restrict__ at)
{
    __shared__ float swc[64*60];                // w2 chunk, transposed [i][m]
    __shared__ __align__(16) float sy3[8*256];
    __shared__ float sy4[8*61];
    const int tid = threadIdx.x;
    const int n0 = blockIdx.x * 8;              // 256 blocks

    #pragma unroll
    for (int l=0;l<2;l++){
        int idx = tid + l*256;                  // 0..511
        int s = idx >> 6, i4 = (idx & 63) << 2;
        const float* src = y3p + (size_t)(n0+s)*256 + i4;
        float4 v = *(const float4*)(src);
        #pragma unroll
        for (int sl=1; sl<KSP; sl++){
            float4 p = *(const float4*)(src + (size_t)sl*NS*DL);
            v.x += p.x; v.y += p.y; v.z += p.z; v.w += p.w;
        }
        const float4 vb = *(const float4*)(b1 + i4);
        const float4 vg = *(const float4*)(g1 + i4);
        const float4 vs = *(const float4*)(bb1 + i4);
        v.x = (v.x + vb.x)*(vg.x*INV_SQRT_BN) + vs.x;  v.x = v.x>=0.f? v.x : 0.01f*v.x;
        v.y = (v.y + vb.y)*(vg.y*INV_SQRT_BN) + vs.y;  v.y = v.y>=0.f? v.y : 0.01f*v.y;
        v.z = (v.z + vb.z)*(vg.z*INV_SQRT_BN) + vs.z;  v.z = v.z>=0.f? v.z : 0.01f*v.z;
        v.w = (v.w + vb.w)*(vg.w*INV_SQRT_BN) + vs.w;  v.w = v.w>=0.f? v.w : 0.01f*v.w;
        *(float4*)(sy3 + s*256 + i4) = v;
    }

    float acc[2]; int ss[2], mm[2];
    #pragma unroll
    for (int l=0;l<2;l++){
        int uu = tid + l*256;
        ss[l]=0; mm[l]=0; acc[l]=0.f;
        if (uu < 480){ ss[l]=uu/60; mm[l]=uu-ss[l]*60; acc[l]=b2[mm[l]]; }
    }

    for (int ch=0; ch<4; ch++){
        const int i0 = ch*64;
        __syncthreads();
        #pragma unroll
        for (int l=0;l<15;l++){
            int idx = tid + l*256;              // 0..3839
            int m = idx >> 6, io = idx & 63;
            swc[io*60 + m] = w2[(size_t)m*256 + i0 + io];
        }
        __syncthreads();
        #pragma unroll
        for (int l=0;l<2;l++){
            int uu = tid + l*256;
            if (uu < 480){
                const float* yy = sy3 + ss[l]*256 + i0;
                float a = acc[l];
                #pragma unroll 8
                for (int io=0; io<64; io++) a += yy[io]*swc[io*60 + mm[l]];
                acc[l] = a;
            }
        }
    }
    __syncthreads();
    #pragma unroll
    for (int l=0;l<2;l++){
        int uu = tid + l*256;
        if (uu < 480){
            float a = acc[l];
            sy4[ss[l]*61 + mm[l]] = a>=0.f? a : 0.01f*a;
        }
    }
    __syncthreads();
    if (tid < 120){
        int s = tid/15, b = tid - s*15;
        const float* y4 = sy4 + s*61 + b*4;
        float ax=y4[0], ay=y4[1], az=y4[2], th=y4[3];
        float nr = sqrtf(ax*ax+ay*ay+az*az);
        float4 o;
        o.x = ax/nr; o.y = ay/nr; o.z = az/nr; o.w = th/81.0f;
        *(float4*)(at + (size_t)(n0+s)*60 + b*4) = o;
    }
}

// ---------------- Kernel 4: per-(n,t) Rodrigues + FK + ba_diff (round-4 form) ----------------
__global__ __launch_bounds__(256)
void pose_kernel(const float* __restrict__ x5, const float* __restrict__ at,
                 float* __restrict__ out)
{
    const int gid = blockIdx.x*256 + threadIdx.x;
    if (gid >= NS*TL) return;
    const int n = gid / TL;
    const int t = gid - n*TL;
    const float ft = (float)t;

    float4 pv[12];
    {
        const float4* src = (const float4*)(x5 + (size_t)gid*48);
        #pragma unroll
        for (int i=0;i<12;i++) pv[i] = src[i];
    }
    float* p = (float*)pv;
    const float4* ab = (const float4*)(at + (size_t)n*60);

    float4 posv[12];
    float* pos = (float*)posv;
    pos[0]=p[0]; pos[1]=p[1]; pos[2]=p[2];      // root
    float ba[15];

    const int PJ[15] = {0,1,2,0,4,5,0,7,8,9,8,11,12,8,14};
    const int CJ[15] = {1,2,3,4,5,6,7,8,9,10,11,12,13,14,15};

    #pragma unroll
    for (int b=0;b<15;b++){
        const int pj = PJ[b], cj = CJ[b];
        float bx = p[cj*3+0]-p[pj*3+0];
        float by = p[cj*3+1]-p[pj*3+1];
        float bz = p[cj*3+2]-p[pj*3+2];
        float bl = sqrtf(bx*bx+by*by+bz*bz);
        float ux = bx/bl, uy = by/bl, uz = bz/bl;
        float mx, my, mz;
        if (b==6 || b==7){                       // FIXED_MASK zeros
            mx=ux; my=uy; mz=uz;
        } else {
            float4 a = ab[b];                    // axis (unit) + theta/81
            float ang = a.w * ft;                // signed angle == reference's |vaa| w/ signed k
            float cs = __cosf(ang), sn = __sinf(ang);   // native trig (measured -13us, absmax unchanged)
            float kd = a.x*ux + a.y*uy + a.z*uz;
            float cx = a.y*uz - a.z*uy;
            float cy = a.z*ux - a.x*uz;
            float cz = a.x*uy - a.y*ux;
            float oc = (1.0f-cs)*kd;
            mx = ux*cs + cx*sn + a.x*oc;
            my = uy*cs + cy*sn + a.y*oc;
            mz = uz*cs + cz*sn + a.z*oc;
        }
        ba[b] = 1.0f - (mx*ux+my*uy+mz*uz);
        pos[cj*3+0] = pos[pj*3+0] + mx*bl;
        pos[cj*3+1] = pos[pj*3+1] + my*bl;
        pos[cj*3+2] = pos[pj*3+2] + mz*bl;
    }

    {
        float4* dst = (float4*)(out + (size_t)gid*48);
        #pragma unroll
        for (int i=0;i<12;i++) dst[i] = posv[i];
    }
    {
        float* bd = out + (size_t)NS*TL*48 + (size_t)gid*15;
        #pragma unroll
        for (int b=0;b<15;b++) bd[b] = ba[b];
    }
}

extern "C" void kernel_launch(void* const* d_in, const int* in_sizes, int n_in,
                              void* d_out, int out_size, void* d_ws, size_t ws_size,
                              hipStream_t stream)
{
    const float* x5    = (const float*)d_in[0];
    const float* noise = (const float*)d_in[1];
    const float* enc_w = (const float*)d_in[2];
    const float* enc_b = (const float*)d_in[3];
    const float* enc_g = (const float*)d_in[4];
    const float* enc_bb= (const float*)d_in[5];
    const float* ln_a  = (const float*)d_in[6];
    const float* ln_b  = (const float*)d_in[7];
    const float* wq = (const float*)d_in[8];
    const float* bq = (const float*)d_in[9];
    const float* wk = (const float*)d_in[10];
    const float* bk = (const float*)d_in[11];
    const float* wv = (const float*)d_in[12];
    const float* bv = (const float*)d_in[13];
    const float* wo = (const float*)d_in[14];
    const float* bo = (const float*)d_in[15];
    const float* w1 = (const float*)d_in[16];
    const float* b1 = (const float*)d_in[17];
    const float* g1 = (const float*)d_in[18];
    const float* bb1= (const float*)d_in[19];
    const float* w2 = (const float*)d_in[20];
    const float* b2 = (const float*)d_in[21];
    float* out = (float*)d_out;

    float* ws = (float*)d_ws;
    float* y2 = ws;                              // 2048*1488 f32 = 12.2 MB
    float* at = y2 + (size_t)NS*KD;              // 2048*60 f32 = 0.49 MB  (ws need: 12.7 MB)

    // gemm1 partial slices (12 x 2MB = 25.2MB) live in d_out (41.8MB) as scratch;
    // head consumes them, then pose overwrites the whole out buffer.
    float* y3p = out;

    attn_kernel<<<NS, 256, 0, stream>>>(x5, noise, enc_w, enc_b, enc_g, enc_bb,
                                        ln_a, ln_b, wq,bq,wk,bk,wv,bv,wo,bo, y2);
    gemm1_kernel<<<128*KSP, 256, 0, stream>>>(y2, w1, y3p);
    head_kernel<<<NS/8, 256, 0, stream>>>(y3p, w2, b2, b1, g1, bb1, at);
    pose_kernel<<<(NS*TL+255)/256, 256, 0, stream>>>(x5, at, out);

    (void)in_sizes; (void)n_in; (void)out_size; (void)ws_size;
}

// Round 7
// 236.148 us; speedup vs baseline: 1.1159x; 1.1159x over previous
//
#include <hip/hip_runtime.h>
#include <math.h>

#define NS   2048
#define TL   81
#define NBN  15
#define DA   48
#define SQL  31
#define KD   1488   // SEQ*D_ATT
#define DL   256
#define MID  40
#define SWLD 52     // 16B-aligned LDS row stride (was 49)

#define INV_SQRT_BN 0.99999500003749969f   // 1/sqrt(1+1e-5)
#define SCALE_ATT   0.35355339059327373f   // 1/sqrt(8)

// ---------------- Kernel 1: per-sample encoder + LN + attention + proj -> y2 ----------------
// Round-0 structure, ONE change: P4/P6 LDS reads b32 -> b128 (stride 52, skewed c-walk).
// Model: attn is LDS-instr-throughput bound (P4 480 b32/thr ~28us, P6 288 ~17us, P5 ~15us = 70us
// measured). b128 halves P4/P6 LDS cycles. No cross-barrier reg arrays (r1-r3 poison).
__global__ __launch_bounds__(256)
void attn_kernel(const float* __restrict__ x5, const float* __restrict__ noise,
                 const float* __restrict__ enc_w, const float* __restrict__ enc_b,
                 const float* __restrict__ enc_g, const float* __restrict__ enc_bb,
                 const float* __restrict__ ln_a, const float* __restrict__ ln_b,
                 const float* __restrict__ wq, const float* __restrict__ bq,
                 const float* __restrict__ wk, const float* __restrict__ bk,
                 const float* __restrict__ wv, const float* __restrict__ bv,
                 const float* __restrict__ wo, const float* __restrict__ bo,
                 float* __restrict__ y2)
{
    __shared__ float s93[96];
    __shared__ __align__(16) float sy[32*SWLD];     // y after enc+relu  [s][f]
    __shared__ __align__(16) float sh[32*SWLD];     // h after LN; reused as ctx
    __shared__ __align__(16) float sW[3*48*SWLD];   // wq|wk|wv staged; arr0 reused for wo
    __shared__ __align__(16) float sQKV[32*148];    // [s][arr*48+f]
    __shared__ float smean[32], sinv[32];

    const int tid = threadIdx.x;
    const int n = blockIdx.x;

    // ---- phase 0: load mid-frame (root-subtracted) + noise; stage wq/wk/wv ----
    if (tid < 93) {
        float v;
        if (tid < 48) {
            const float* base = x5 + ((size_t)n*TL + MID)*48;
            v = base[tid] - base[tid % 3];          // x5 - root (joint 0)
        } else {
            v = noise[(size_t)n*45 + (tid-48)];
        }
        s93[tid] = v;
    }
    #pragma unroll
    for (int l=0; l<9; l++){
        int idx = tid + l*256;                      // 0..2303
        int f = idx/48, c = idx - f*48;
        int o = f*SWLD + c;
        sW[o]             = wq[idx];
        sW[48*SWLD  + o]  = wk[idx];
        sW[96*SWLD  + o]  = wv[idx];
    }
    __syncthreads();

    // ---- phase 1: encoder + BN + relu ----
    for (int idx=tid; idx<SQL*DA; idx+=256){
        int s = idx/48, f = idx - s*48;
        float a = enc_b[f]
                + s93[s*3+0]*enc_w[f*3+0]
                + s93[s*3+1]*enc_w[f*3+1]
                + s93[s*3+2]*enc_w[f*3+2];
        float v = a * (enc_g[f]*INV_SQRT_BN) + enc_bb[f];
        sy[s*SWLD+f] = fmaxf(v, 0.0f);
    }
    __syncthreads();

    // ---- phase 2: layer-norm stats (divisor 47, eps on std) ----
    if (tid < SQL){
        float m = 0.f;
        for (int f=0; f<48; f++) m += sy[tid*SWLD+f];
        m *= (1.0f/48.0f);
        float vs = 0.f;
        for (int f=0; f<48; f++){ float d = sy[tid*SWLD+f]-m; vs += d*d; }
        float sd = sqrtf(vs * (1.0f/47.0f));
        smean[tid] = m;
        sinv[tid]  = 1.0f/(sd + 1e-6f);
    }
    __syncthreads();

    // ---- phase 3: apply LN ----
    for (int idx=tid; idx<SQL*DA; idx+=256){
        int s = idx/48, f = idx - s*48;
        sh[s*SWLD+f] = ln_a[f]*(sy[s*SWLD+f]-smean[s])*sinv[s] + ln_b[f];
    }
    __syncthreads();

    // ---- phase 4: QKV (4s x 6f tiles, 192 threads, b128 reads, skewed c-walk) ----
    if (tid < 192){
        const int sg  = tid/24;                     // 0..7 -> rows sg*4..sg*4+3
        const int rem = tid - sg*24;
        const int arr = rem >> 3;                   // 0..2 -> q,k,v
        const int fg  = rem & 7;                    // 0..7 -> cols fg*6..fg*6+5
        const int f0  = fg*6;
        const int s0  = sg*4;
        const float* wb = sW + arr*48*SWLD + f0*SWLD;
        const float* hb = sh + s0*SWLD;
        float acc[4][6];
        #pragma unroll
        for (int j=0;j<4;j++)
            #pragma unroll
            for (int i=0;i<6;i++) acc[j][i]=0.f;
        for (int cc=0; cc<12; cc++){
            const int c0 = 4*((fg + cc) % 12);      // skew: fg groups start at different banks
            float4 h0 = *(const float4*)(hb + 0*SWLD + c0);
            float4 h1 = *(const float4*)(hb + 1*SWLD + c0);
            float4 h2 = *(const float4*)(hb + 2*SWLD + c0);
            float4 h3 = *(const float4*)(hb + 3*SWLD + c0);
            #pragma unroll
            for (int i=0;i<6;i++){
                float4 w = *(const float4*)(wb + i*SWLD + c0);
                acc[0][i] += h0.x*w.x + h0.y*w.y + h0.z*w.z + h0.w*w.w;
                acc[1][i] += h1.x*w.x + h1.y*w.y + h1.z*w.z + h1.w*w.w;
                acc[2][i] += h2.x*w.x + h2.y*w.y + h2.z*w.z + h2.w*w.w;
                acc[3][i] += h3.x*w.x + h3.y*w.y + h3.z*w.z + h3.w*w.w;
            }
        }
        const float* bias = (arr==0)? bq : (arr==1? bk : bv);
        #pragma unroll
        for (int i=0;i<6;i++){
            float b = bias[f0+i];
            int col = arr*48 + f0 + i;
            sQKV[(s0+0)*148 + col] = acc[0][i] + b;
            sQKV[(s0+1)*148 + col] = acc[1][i] + b;
            sQKV[(s0+2)*148 + col] = acc[2][i] + b;
            sQKV[(s0+3)*148 + col] = acc[3][i] + b;  // s=31 row is scratch, never read
        }
    }
    __syncthreads();

    // ---- phase 5: stage wo into sW arr0 (dead); attention (186 threads) -> ctx into sh ----
    #pragma unroll
    for (int l=0; l<9; l++){
        int idx = tid + l*256;
        sW[(idx/48)*SWLD + (idx%48)] = wo[idx];
    }
    if (tid < 186){
        const int hd = tid/31, qi = tid - (tid/31)*31;
        const float4 q0 = *(const float4*)(sQKV + qi*148 + hd*8);
        const float4 q1 = *(const float4*)(sQKV + qi*148 + hd*8 + 4);
        float sc[31]; float mx = -1e30f;
        for (int ki=0; ki<31; ki++){
            const float4 k0 = *(const float4*)(sQKV + ki*148 + 48 + hd*8);
            const float4 k1 = *(const float4*)(sQKV + ki*148 + 48 + hd*8 + 4);
            float d = q0.x*k0.x + q0.y*k0.y + q0.z*k0.z + q0.w*k0.w
                    + q1.x*k1.x + q1.y*k1.y + q1.z*k1.z + q1.w*k1.w;
            d *= SCALE_ATT;
            sc[ki] = d; mx = fmaxf(mx, d);
        }
        float ssum = 0.f;
        for (int ki=0; ki<31; ki++){ float e = expf(sc[ki]-mx); sc[ki]=e; ssum += e; }
        float rin = 1.0f/ssum;
        float4 c0 = {0,0,0,0}, c1 = {0,0,0,0};
        for (int ki=0; ki<31; ki++){
            float p = sc[ki];
            const float4 v0 = *(const float4*)(sQKV + ki*148 + 96 + hd*8);
            const float4 v1 = *(const float4*)(sQKV + ki*148 + 96 + hd*8 + 4);
            c0.x += p*v0.x; c0.y += p*v0.y; c0.z += p*v0.z; c0.w += p*v0.w;
            c1.x += p*v1.x; c1.y += p*v1.y; c1.z += p*v1.z; c1.w += p*v1.w;
        }
        float* cb = sh + qi*SWLD + hd*8;            // ctx overwrites h (dead); 16B-aligned
        float4 o0, o1;
        o0.x=c0.x*rin; o0.y=c0.y*rin; o0.z=c0.z*rin; o0.w=c0.w*rin;
        o1.x=c1.x*rin; o1.y=c1.y*rin; o1.z=c1.z*rin; o1.w=c1.w*rin;
        *(float4*)(cb)   = o0;
        *(float4*)(cb+4) = o1;
    }
    __syncthreads();

    // ---- phase 6: proj + residual -> y2 (2s x 4f tiles, 192 threads, b128, skewed) ----
    if (tid < 192){
        const int sg = tid/12;                      // 0..15 -> rows sg*2, sg*2+1
        const int fg = tid - sg*12;                 // 0..11 -> cols fg*4..fg*4+3
        const int f0 = fg*4;
        const float* wb = sW + f0*SWLD;             // wo (slot 0)
        const float* cb = sh + sg*2*SWLD;           // ctx
        float a0[4]={0,0,0,0}, a1[4]={0,0,0,0};
        for (int cc=0; cc<12; cc++){
            const int c0 = 4*((fg + cc) % 12);
            float4 x0 = *(const float4*)(cb + c0);
            float4 x1 = *(const float4*)(cb + SWLD + c0);
            #pragma unroll
            for (int i=0;i<4;i++){
                float4 w = *(const float4*)(wb + i*SWLD + c0);
                a0[i] += x0.x*w.x + x0.y*w.y + x0.z*w.z + x0.w*w.w;
                a1[i] += x1.x*w.x + x1.y*w.y + x1.z*w.z + x1.w*w.w;
            }
        }
        {
            int s = sg*2;
            if (s < 31){
                float* dst = y2 + (size_t)n*KD + s*48 + f0;
                const float* yb = sy + s*SWLD + f0;
                #pragma unroll
                for (int i=0;i<4;i++) dst[i] = yb[i] + a0[i] + bo[f0+i];
            }
        }
        {
            int s = sg*2+1;
            if (s < 31){
                float* dst = y2 + (size_t)n*KD + s*48 + f0;
                const float* yb = sy + s*SWLD + f0;
                #pragma unroll
                for (int i=0;i<4;i++) dst[i] = yb[i] + a1[i] + bo[f0+i];
            }
        }
    }
}

// ---------------- Kernel 2: C = y2 @ w1^T, K-split 6 (round-4 anchor form) ----------------
#define KSP 6
#define KPS 248     // 1488/6
#define KCH 8

__global__ __launch_bounds__(256)
void gemm1_kernel(const float* __restrict__ y2, const float* __restrict__ w1,
                  float* __restrict__ y3p)
{
    __shared__ __align__(16) float sB[KCH*256];     // [kk][n]  8KB
    __shared__ __align__(16) float sA[KCH*20];      // [kk][m]  640B
    const int tid = threadIdx.x;
    const int bx = blockIdx.x;                      // 768 blocks
    const int m0 = (bx & 127) * 16;
    const int split = bx >> 7;                      // 0..5
    const int ks0 = split * KPS;
    const int c0 = (tid & 15)*4 + (tid >> 6)*64;    // output cols c0..c0+3
    const int r0 = ((tid >> 4) & 3)*4;              // output rows r0..r0+3

    const int bn = tid >> 1;                        // B staging: row within half
    const int bg = (tid & 1)*4;                     // kq
    const int ar = tid >> 1;                        // A staging (tid<32)
    const int ag = (tid & 1)*4;

    float acc[4][4];
    #pragma unroll
    for (int i=0;i<4;i++)
        #pragma unroll
        for (int j=0;j<4;j++) acc[i][j]=0.f;

    for (int ch=0; ch<31; ch++){
        const int k0 = ks0 + ch*KCH;
        // global loads first (latency overlapped with other blocks' compute)
        float4 b0v = *(const float4*)(w1 + (size_t)bn*KD        + k0 + bg);
        float4 b1v = *(const float4*)(w1 + (size_t)(bn+128)*KD  + k0 + bg);
        float4 av;
        if (tid < 32) av = *(const float4*)(y2 + (size_t)(m0+ar)*KD + k0 + ag);
        __syncthreads();
        // transposed stores: bank = n%32 across lanes -> 2-way (free)
        sB[(bg+0)*256 + bn] = b0v.x;  sB[(bg+1)*256 + bn] = b0v.y;
        sB[(bg+2)*256 + bn] = b0v.z;  sB[(bg+3)*256 + bn] = b0v.w;
        sB[(bg+0)*256 + bn+128] = b1v.x;  sB[(bg+1)*256 + bn+128] = b1v.y;
        sB[(bg+2)*256 + bn+128] = b1v.z;  sB[(bg+3)*256 + bn+128] = b1v.w;
        if (tid < 32){
            sA[(ag+0)*20 + ar] = av.x;  sA[(ag+1)*20 + ar] = av.y;
            sA[(ag+2)*20 + ar] = av.z;  sA[(ag+3)*20 + ar] = av.w;
        }
        __syncthreads();
        #pragma unroll
        for (int kk=0; kk<KCH; kk++){
            float4 b = *(const float4*)(sB + kk*256 + c0);  // 16 addr x 4-lane bcast
            float4 a = *(const float4*)(sA + kk*20 + r0);   // 4 addr broadcast
            acc[0][0] += a.x*b.x; acc[0][1] += a.x*b.y; acc[0][2] += a.x*b.z; acc[0][3] += a.x*b.w;
            acc[1][0] += a.y*b.x; acc[1][1] += a.y*b.y; acc[1][2] += a.y*b.z; acc[1][3] += a.y*b.w;
            acc[2][0] += a.z*b.x; acc[2][1] += a.z*b.y; acc[2][2] += a.z*b.z; acc[2][3] += a.z*b.w;
            acc[3][0] += a.w*b.x; acc[3][1] += a.w*b.y; acc[3][2] += a.w*b.z; acc[3][3] += a.w*b.w;
        }
    }

    float* dst = y3p + (size_t)split*NS*DL;
    #pragma unroll
    for (int i=0;i<4;i++){
        float4 v; v.x=acc[i][0]; v.y=acc[i][1]; v.z=acc[i][2]; v.w=acc[i][3];
        *(float4*)(dst + (size_t)(m0+r0+i)*DL + c0) = v;
    }
}

// ---------------- Kernel 3: sum K-splits + bias/BN/leaky; y4 = leaky(y3 @ w2^T + b2); axis/theta ----------------
__global__ __launch_bounds__(256)
void head_kernel(const float* __restrict__ y3p, const float* __restrict__ w2,
                 const float* __restrict__ b2, const float* __restrict__ b1,
                 const float* __restrict__ g1, const float* __restrict__ bb1,
                 float* __restrict__ at)
{
    __shared__ float swc[64*60];                // w2 chunk, transposed [i][m]
    __shared__ __align__(16) float sy3[8*256];
    __shared__ float sy4[8*61];
    const int tid = threadIdx.x;
    const int n0 = blockIdx.x * 8;              // 256 blocks

    #pragma unroll
    for (int l=0;l<2;l++){
        int idx = tid + l*256;                  // 0..511
        int s = idx >> 6, i4 = (idx & 63) << 2;
        const float* src = y3p + (size_t)(n0+s)*256 + i4;
        float4 v = *(const float4*)(src);
        #pragma unroll
        for (int sl=1; sl<6; sl++){
            float4 p = *(const float4*)(src + (size_t)sl*NS*DL);
            v.x += p.x; v.y += p.y; v.z += p.z; v.w += p.w;
        }
        const float4 vb = *(const float4*)(b1 + i4);
        const float4 vg = *(const float4*)(g1 + i4);
        const float4 vs = *(const float4*)(bb1 + i4);
        v.x = (v.x + vb.x)*(vg.x*INV_SQRT_BN) + vs.x;  v.x = v.x>=0.f? v.x : 0.01f*v.x;
        v.y = (v.y + vb.y)*(vg.y*INV_SQRT_BN) + vs.y;  v.y = v.y>=0.f? v.y : 0.01f*v.y;
        v.z = (v.z + vb.z)*(vg.z*INV_SQRT_BN) + vs.z;  v.z = v.z>=0.f? v.z : 0.01f*v.z;
        v.w = (v.w + vb.w)*(vg.w*INV_SQRT_BN) + vs.w;  v.w = v.w>=0.f? v.w : 0.01f*v.w;
        *(float4*)(sy3 + s*256 + i4) = v;
    }

    float acc[2]; int ss[2], mm[2];
    #pragma unroll
    for (int l=0;l<2;l++){
        int uu = tid + l*256;
        ss[l]=0; mm[l]=0; acc[l]=0.f;
        if (uu < 480){ ss[l]=uu/60; mm[l]=uu-ss[l]*60; acc[l]=b2[mm[l]]; }
    }

    for (int ch=0; ch<4; ch++){
        const int i0 = ch*64;
        __syncthreads();
        #pragma unroll
        for (int l=0;l<15;l++){
            int idx = tid + l*256;              // 0..3839
            int m = idx >> 6, io = idx & 63;
            swc[io*60 + m] = w2[(size_t)m*256 + i0 + io];
        }
        __syncthreads();
        #pragma unroll
        for (int l=0;l<2;l++){
            int uu = tid + l*256;
            if (uu < 480){
                const float* yy = sy3 + ss[l]*256 + i0;
                float a = acc[l];
                #pragma unroll 8
                for (int io=0; io<64; io++) a += yy[io]*swc[io*60 + mm[l]];
                acc[l] = a;
            }
        }
    }
    __syncthreads();
    #pragma unroll
    for (int l=0;l<2;l++){
        int uu = tid + l*256;
        if (uu < 480){
            float a = acc[l];
            sy4[ss[l]*61 + mm[l]] = a>=0.f? a : 0.01f*a;
        }
    }
    __syncthreads();
    if (tid < 120){
        int s = tid/15, b = tid - s*15;
        const float* y4 = sy4 + s*61 + b*4;
        float ax=y4[0], ay=y4[1], az=y4[2], th=y4[3];
        float nr = sqrtf(ax*ax+ay*ay+az*az);
        float4 o;
        o.x = ax/nr; o.y = ay/nr; o.z = az/nr; o.w = th/81.0f;
        *(float4*)(at + (size_t)(n0+s)*60 + b*4) = o;
    }
}

// ---------------- Kernel 4: per-(n,t) Rodrigues + FK + ba_diff (round-4 form) ----------------
__global__ __launch_bounds__(256)
void pose_kernel(const float* __restrict__ x5, const float* __restrict__ at,
                 float* __restrict__ out)
{
    const int gid = blockIdx.x*256 + threadIdx.x;
    if (gid >= NS*TL) return;
    const int n = gid / TL;
    const int t = gid - n*TL;
    const float ft = (float)t;

    float4 pv[12];
    {
        const float4* src = (const float4*)(x5 + (size_t)gid*48);
        #pragma unroll
        for (int i=0;i<12;i++) pv[i] = src[i];
    }
    float* p = (float*)pv;
    const float4* ab = (const float4*)(at + (size_t)n*60);

    float4 posv[12];
    float* pos = (float*)posv;
    pos[0]=p[0]; pos[1]=p[1]; pos[2]=p[2];      // root
    float ba[15];

    const int PJ[15] = {0,1,2,0,4,5,0,7,8,9,8,11,12,8,14};
    const int CJ[15] = {1,2,3,4,5,6,7,8,9,10,11,12,13,14,15};

    #pragma unroll
    for (int b=0;b<15;b++){
        const int pj = PJ[b], cj = CJ[b];
        float bx = p[cj*3+0]-p[pj*3+0];
        float by = p[cj*3+1]-p[pj*3+1];
        float bz = p[cj*3+2]-p[pj*3+2];
        float bl = sqrtf(bx*bx+by*by+bz*bz);
        float ux = bx/bl, uy = by/bl, uz = bz/bl;
        float mx, my, mz;
        if (b==6 || b==7){                       // FIXED_MASK zeros
            mx=ux; my=uy; mz=uz;
        } else {
            float4 a = ab[b];                    // axis (unit) + theta/81
            float ang = a.w * ft;                // signed angle == reference's |vaa| w/ signed k
            float cs = __cosf(ang), sn = __sinf(ang);   // native trig (measured -13us, absmax unchanged)
            float kd = a.x*ux + a.y*uy + a.z*uz;
            float cx = a.y*uz - a.z*uy;
            float cy = a.z*ux - a.x*uz;
            float cz = a.x*uy - a.y*ux;
            float oc = (1.0f-cs)*kd;
            mx = ux*cs + cx*sn + a.x*oc;
            my = uy*cs + cy*sn + a.y*oc;
            mz = uz*cs + cz*sn + a.z*oc;
        }
        ba[b] = 1.0f - (mx*ux+my*uy+mz*uz);
        pos[cj*3+0] = pos[pj*3+0] + mx*bl;
        pos[cj*3+1] = pos[pj*3+1] + my*bl;
        pos[cj*3+2] = pos[pj*3+2] + mz*bl;
    }

    {
        float4* dst = (float4*)(out + (size_t)gid*48);
        #pragma unroll
        for (int i=0;i<12;i++) dst[i] = posv[i];
    }
    {
        float* bd = out + (size_t)NS*TL*48 + (size_t)gid*15;
        #pragma unroll
        for (int b=0;b<15;b++) bd[b] = ba[b];
    }
}

extern "C" void kernel_launch(void* const* d_in, const int* in_sizes, int n_in,
                              void* d_out, int out_size, void* d_ws, size_t ws_size,
                              hipStream_t stream)
{
    const float* x5    = (const float*)d_in[0];
    const float* noise = (const float*)d_in[1];
    const float* enc_w = (const float*)d_in[2];
    const float* enc_b = (const float*)d_in[3];
    const float* enc_g = (const float*)d_in[4];
    const float* enc_bb= (const float*)d_in[5];
    const float* ln_a  = (const float*)d_in[6];
    const float* ln_b  = (const float*)d_in[7];
    const float* wq = (const float*)d_in[8];
    const float* bq = (const float*)d_in[9];
    const float* wk = (const float*)d_in[10];
    const float* bk = (const float*)d_in[11];
    const float* wv = (const float*)d_in[12];
    const float* bv = (const float*)d_in[13];
    const float* wo = (const float*)d_in[14];
    const float* bo = (const float*)d_in[15];
    const float* w1 = (const float*)d_in[16];
    const float* b1 = (const float*)d_in[17];
    const float* g1 = (const float*)d_in[18];
    const float* bb1= (const float*)d_in[19];
    const float* w2 = (const float*)d_in[20];
    const float* b2 = (const float*)d_in[21];
    float* out = (float*)d_out;

    float* ws = (float*)d_ws;
    float* y2 = ws;                              // 2048*1488 f32 = 12.2 MB
    float* at = y2 + (size_t)NS*KD;              // 2048*60 f32 = 0.49 MB  (ws need: 12.7 MB)

    // gemm1 partial slices (6 x 2MB) live in d_out as scratch; head consumes them,
    // then pose overwrites the whole out buffer. Stream order serializes all three.
    float* y3p = out;

    attn_kernel<<<NS, 256, 0, stream>>>(x5, noise, enc_w, enc_b, enc_g, enc_bb,
                                        ln_a, ln_b, wq,bq,wk,bk,wv,bv,wo,bo, y2);
    gemm1_kernel<<<128*KSP, 256, 0, stream>>>(y2, w1, y3p);
    head_kernel<<<NS/8, 256, 0, stream>>>(y3p, w2, b2, b1, g1, bb1, at);
    pose_kernel<<<(NS*TL+255)/256, 256, 0, stream>>>(x5, at, out);

    (void)in_sizes; (void)n_in; (void)out_size; (void)ws_size;
}